// Round 14
// baseline (170.809 us; speedup 1.0000x reference)
//
#include <hip/hip_runtime.h>
#include <hip/hip_bf16.h>
#include <stdint.h>

// MoE gate: T=524288, D=256, E=64, groups=2x32, topk=4.
// Pass 1: logits^T = W @ x^T via mfma_f32_16x16x32_bf16. W and x each split
//   into 2 bf16 truncation levels; 4 cross terms; dropped-term sigma ~1e-6
//   << DELTA=1e-4. W-split staged once per block into LDS (v12 layout).
//   x staged through WAVE-PRIVATE LDS double-buffers via global_load_lds:
//   each staging instruction covers 8 token-rows x full 128B line (every
//   line touched exactly ONCE); piece-swizzle (p^row) stays within the
//   line. No __syncthreads in the loop; counted vmcnt only. Fragment reads
//   via C++ LDS loads (compiler-addressed ds_read_b128; v13's bug was raw
//   offsets missing the XL base). WAR guard: lgkmcnt(0)+sched_barrier
//   before re-staging the just-read buffer.
// Pass 2: tokens with selection margin < DELTA recomputed exactly (np-order
//   fmaf chain) by fix_kernel (~1% of tokens).

typedef __attribute__((ext_vector_type(8))) short bf16x8;
typedef __attribute__((ext_vector_type(4))) float f32x4;
typedef __attribute__((ext_vector_type(4))) int i32x4;

#define SPLIT_OFF 1024
#define LIST_OFF 102400
#define DELTA 1e-4f

__device__ __forceinline__ f32x4 mf(const i32x4& a, const i32x4& b,
                                    const f32x4& c) {
  return __builtin_amdgcn_mfma_f32_16x16x32_bf16(
      __builtin_bit_cast(bf16x8, a), __builtin_bit_cast(bf16x8, b), c, 0, 0, 0);
}

// low short = hi16(e0), high short = hi16(e1)
__device__ __forceinline__ int packhi(unsigned e0, unsigned e1) {
  return (int)__builtin_amdgcn_perm(e1, e0, 0x07060302u);
}

__device__ __forceinline__ void gload16(const void* g, void* l) {
  __builtin_amdgcn_global_load_lds(
      (const __attribute__((address_space(1))) void*)g,
      (__attribute__((address_space(3))) void*)l, 16, 0, 0);
}

// W -> 2 bf16 truncation levels (h, m), packed in MFMA A-fragment
// chunk-major layout with the K-PERMUTED mapping (unchanged from v12):
// fragment slot kk of lane (lg*16+le) in frag(c, q=v*4+nt) holds
// W_v[e=nt*16+le][k = c*32 + (kk>>2)*16 + lg*4 + (kk&3)].
__global__ void split_w(const float* __restrict__ W,
                        unsigned short* __restrict__ ws, int n,
                        int* __restrict__ meta) {
  int i = blockIdx.x * 256 + threadIdx.x;
  if (i == 0) meta[0] = 0;
  if (i >= n) return;
  float w = W[i];
  unsigned u = __float_as_uint(w);
  unsigned uh = u & 0xFFFF0000u;
  float rf = w - __uint_as_float(uh);  // exact
  unsigned short lv[2];
  lv[0] = (unsigned short)(uh >> 16);
  lv[1] = (unsigned short)(__float_as_uint(rf) >> 16);
  int e = i >> 8, k = i & 255;
  int nt = e >> 4, le = e & 15;
  int c = k >> 5, kc = k & 31;
  int half = kc >> 4, lg = (kc >> 2) & 3, pos = kc & 3;
  int kk = half * 4 + pos;
  int lane = lg * 16 + le;
#pragma unroll
  for (int v = 0; v < 2; ++v)
    ws[(((c * 8 + v * 4 + nt) * 64) + lane) * 8 + kk] = lv[v];
}

struct XF2 { i32x4 h, m; };

__device__ __forceinline__ XF2 split2(f32x4 a, f32x4 b) {
  float xs[8] = {a[0], a[1], a[2], a[3], b[0], b[1], b[2], b[3]};
  XF2 f;
#pragma unroll
  for (int wd = 0; wd < 4; ++wd) {
    unsigned u0 = __float_as_uint(xs[2 * wd]);
    unsigned u1 = __float_as_uint(xs[2 * wd + 1]);
    f.h[wd] = packhi(u0, u1);
    float r0 = xs[2 * wd] - __uint_as_float(u0 & 0xFFFF0000u);      // exact
    float r1 = xs[2 * wd + 1] - __uint_as_float(u1 & 0xFFFF0000u);  // exact
    f.m[wd] = packhi(__float_as_uint(r0), __float_as_uint(r1));
  }
  return f;
}

#define WAITV(NSTR)                                         \
  do {                                                      \
    asm volatile("s_waitcnt vmcnt(" NSTR ")" ::: "memory"); \
    __builtin_amdgcn_sched_barrier(0);                      \
  } while (0)

__global__ __launch_bounds__(512, 2) void gate_kernel(
    const float* __restrict__ x, const unsigned short* __restrict__ wsp,
    float* __restrict__ out, int* __restrict__ meta, int* __restrict__ list,
    int cap, int T) {
  __shared__ i32x4 WL[4096];  // 64 KB: W-split fragments, chunk-major
  __shared__ i32x4 XL[4096];  // 64 KB: x staging, wave-private 8 KB/wave

  const int t = threadIdx.x;
  const int lane = t & 63;
  const int wid = t >> 6;    // 0..7
  const int le = lane & 15;  // token col / expert row within 16-tile
  const int lg = lane >> 4;  // k-quad group
  const int tokb = blockIdx.x * 256 + wid * 32;

  // staging: instr q covers tokens tokb+q*8 .. +7, FULL 128B line per row.
  // lane -> row srow=lane>>3, phys piece lane&7 holds logical piece
  // (lane&7)^srow (swizzle stays within the line).
  const int srow = lane >> 3;
  const int spiece = (lane & 7) ^ srow;
  const float* xg[4];
#pragma unroll
  for (int q = 0; q < 4; ++q)
    xg[q] = x + (size_t)(tokb + q * 8 + srow) * 256 + spiece * 4;

  char* XW = (char*)XL + wid * 8192;  // this wave's 8 KB region

  // fragment read offsets (within XW, + parity*4096):
  // logical piece P of row r=h*16+le lives at byte
  // (2h+(le>>3))*1024 + (le&7)*128 + ((P^(le&7))<<4).
  const int s7 = le & 7;
  const int abase = (le >> 3) * 1024 + s7 * 128;
  const int o00 = abase + ((lg ^ s7) << 4);          // h=0, piece lg
  const int o01 = abase + (((lg + 4) ^ s7) << 4);    // h=0, piece lg+4
  const int o10 = o00 + 2048;                        // h=1
  const int o11 = o01 + 2048;

  f32x4 acc[4][2];  // [nt][tile]
#pragma unroll
  for (int nt = 0; nt < 4; ++nt)
#pragma unroll
    for (int t2 = 0; t2 < 2; ++t2) acc[nt][t2] = (f32x4)0.0f;

#define STAGE_X(c)                                                  \
  do {                                                              \
    char* xd_ = XW + (((c) & 1) << 12);                             \
    gload16(xg[0] + (c) * 32, xd_);                                 \
    gload16(xg[1] + (c) * 32, xd_ + 1024);                          \
    gload16(xg[2] + (c) * 32, xd_ + 2048);                          \
    gload16(xg[3] + (c) * 32, xd_ + 3072);                          \
  } while (0)

  // ITER c: wait x(c) staged; C++ ds_reads of 4 frags; lgkmcnt(0) (buffer
  // may then be overwritten); stage x(c+2) into the freed buffer; split;
  // 32 MFMAs from LDS W fragments. No per-ITER barriers.
#define ITER(c, NSTR)                                               \
  {                                                                 \
    WAITV(NSTR);                                                    \
    const char* xb_ = XW + (((c) & 1) << 12);                       \
    f32x4 r00 = *(const f32x4*)(xb_ + o00);                         \
    f32x4 r01 = *(const f32x4*)(xb_ + o01);                         \
    f32x4 r10 = *(const f32x4*)(xb_ + o10);                         \
    f32x4 r11 = *(const f32x4*)(xb_ + o11);                         \
    asm volatile("s_waitcnt lgkmcnt(0)" ::: "memory");              \
    __builtin_amdgcn_sched_barrier(0);                              \
    if ((c) + 2 < 8) STAGE_X((c) + 2);                              \
    XF2 b0 = split2(r00, r01);                                      \
    XF2 b1 = split2(r10, r11);                                      \
    _Pragma("unroll") for (int nt = 0; nt < 4; ++nt) {              \
      i32x4 ah = WL[(((c) * 8 + nt) << 6) + lane];                  \
      i32x4 am = WL[(((c) * 8 + 4 + nt) << 6) + lane];              \
      acc[nt][0] = mf(ah, b0.h, acc[nt][0]);                        \
      acc[nt][0] = mf(ah, b0.m, acc[nt][0]);                        \
      acc[nt][0] = mf(am, b0.h, acc[nt][0]);                        \
      acc[nt][0] = mf(am, b0.m, acc[nt][0]);                        \
      acc[nt][1] = mf(ah, b1.h, acc[nt][1]);                        \
      acc[nt][1] = mf(ah, b1.m, acc[nt][1]);                        \
      acc[nt][1] = mf(am, b1.h, acc[nt][1]);                        \
      acc[nt][1] = mf(am, b1.m, acc[nt][1]);                        \
    }                                                               \
  }

  // ---- prologue: W gload_lds (8/thread, 64KB/block), then x chunks 0,1;
  // counted wait completes exactly W (x stays in flight); raw barrier. ----
  {
    const char* wsrc = (const char*)wsp + t * 16;
    char* wdst = (char*)WL + t * 16;
#pragma unroll
    for (int i = 0; i < 8; ++i) gload16(wsrc + i * 8192, wdst + i * 8192);
  }
  STAGE_X(0);
  STAGE_X(1);
  WAITV("8");
  __builtin_amdgcn_s_barrier();

  ITER(0, "4");
  ITER(1, "4");
  ITER(2, "4");
  ITER(3, "4");
  ITER(4, "4");
  ITER(5, "4");
  ITER(6, "4");
  ITER(7, "0");

  // epilogue: D col=token(le), row=expert=nt*16+4*lg+j. LOGIT-domain select.
#pragma unroll
  for (int tt = 0; tt < 2; ++tt) {
    float l[16];
#pragma unroll
    for (int nt = 0; nt < 4; ++nt)
#pragma unroll
      for (int j = 0; j < 4; ++j) l[nt * 4 + j] = acc[nt][tt][j];

    float g0 = l[0], g1 = l[8];
#pragma unroll
    for (int j = 1; j < 8; ++j) {
      g0 = fmaxf(g0, l[j]);
      g1 = fmaxf(g1, l[8 + j]);
    }
    g0 = fmaxf(g0, __shfl_xor(g0, 16));
    g0 = fmaxf(g0, __shfl_xor(g0, 32));
    g1 = fmaxf(g1, __shfl_xor(g1, 16));
    g1 = fmaxf(g1, __shfl_xor(g1, 32));
    const int g = (g1 > g0) ? 1 : 0;  // tie -> group 0
    const float m = fmaxf(g0, g1);

    float sum = 0.f;
#pragma unroll
    for (int k = 0; k < 16; ++k) sum += __expf(l[k] - m);
    sum += __shfl_xor(sum, 16);
    sum += __shfl_xor(sum, 32);
    const float inv = 1.0f / sum;

    float c[8];
    int ce[8];
#pragma unroll
    for (int j2 = 0; j2 < 8; ++j2) {
      c[j2] = l[g * 8 + j2];
      ce[j2] = (2 * g + (j2 >> 2)) * 16 + 4 * lg + (j2 & 3);
    }

    float v5[5];
    int e5[5];
#pragma unroll
    for (int it = 0; it < 5; ++it) {
      float bv = c[0];
      int be = ce[0];
#pragma unroll
      for (int j2 = 1; j2 < 8; ++j2) {  // strict > keeps lowest index
        bool gt = c[j2] > bv;
        bv = gt ? c[j2] : bv;
        be = gt ? ce[j2] : be;
      }
#pragma unroll
      for (int st = 0; st < 2; ++st) {
        int msk = 16 << st;
        float ov = __shfl_xor(bv, msk);
        int oe = __shfl_xor(be, msk);
        bool tk = (ov > bv) || (ov == bv && oe < be);
        bv = tk ? ov : bv;
        be = tk ? oe : be;
      }
      v5[it] = bv;
      e5[it] = be;
#pragma unroll
      for (int j2 = 0; j2 < 8; ++j2)
        c[j2] = (ce[j2] == be) ? -3.0e38f : c[j2];
    }

    float ming = fabsf(g0 - g1);
#pragma unroll
    for (int it = 0; it < 4; ++it) ming = fminf(ming, v5[it] - v5[it + 1]);

    if (lg == 0) {
      size_t trow = (size_t)tokb + tt * 16 + le;
      *(float4*)&out[trow * 4] =
          make_float4(__expf(v5[0] - m) * inv, __expf(v5[1] - m) * inv,
                      __expf(v5[2] - m) * inv, __expf(v5[3] - m) * inv);
      *(float4*)&out[(size_t)T * 4 + trow * 4] = make_float4(
          (float)e5[0], (float)e5[1], (float)e5[2], (float)e5[3]);
      if (ming < DELTA) {
        int p = atomicAdd(meta, 1);
        if (p < cap) list[p] = (int)trow;
      }
    }
  }
}

// exact recompute of flagged tokens: one wave per token, lane = expert.
__global__ __launch_bounds__(64) void fix_kernel(
    const float* __restrict__ x, const float* __restrict__ W,
    float* __restrict__ out, const int* __restrict__ meta,
    const int* __restrict__ list, int cap, int T) {
  const int e = threadIdx.x;
  int cnt = meta[0];
  cnt = cnt < cap ? cnt : cap;
  for (int i = blockIdx.x; i < cnt; i += gridDim.x) {
    const int tok = list[i];
    const float* xr = x + (size_t)tok * 256;
    const float* wr = W + (size_t)e * 256;
    float acc = 0.f;
#pragma unroll 8
    for (int d = 0; d < 256; d += 4) {  // single-acc ascending-d fmaf chain
      float4 xv = *(const float4*)(xr + d);
      float4 wv = *(const float4*)(wr + d);
      acc = fmaf(xv.x, wv.x, acc);
      acc = fmaf(xv.y, wv.y, acc);
      acc = fmaf(xv.z, wv.z, acc);
      acc = fmaf(xv.w, wv.w, acc);
    }
    float gm = acc;
#pragma unroll
    for (int st = 0; st < 5; ++st) gm = fmaxf(gm, __shfl_xor(gm, 1 << st));
    float om = __shfl_xor(gm, 32);
    float g0 = (e < 32) ? gm : om;
    float g1 = (e < 32) ? om : gm;
    const int g = (g1 > g0) ? 1 : 0;
    const float m = fmaxf(g0, g1);
    float sum = __expf(acc - m);
#pragma unroll
    for (int st = 0; st < 6; ++st) sum += __shfl_xor(sum, 1 << st);
    const float inv = 1.0f / sum;

    float cand = ((e >> 5) == g) ? acc : -3.0e38f;
    float w4[4], i4[4];
#pragma unroll
    for (int it = 0; it < 4; ++it) {
      float bv = cand;
      int be = e;
#pragma unroll
      for (int st = 0; st < 6; ++st) {
        int msk = 1 << st;
        float ov = __shfl_xor(bv, msk);
        int oe = __shfl_xor(be, msk);
        bool tk = (ov > bv) || (ov == bv && oe < be);
        bv = tk ? ov : bv;
        be = tk ? oe : be;
      }
      w4[it] = __expf(bv - m) * inv;
      i4[it] = (float)be;
      if (e == be) cand = -3.0e38f;
    }
    if (e == 0) {
      *(float4*)&out[(size_t)tok * 4] = make_float4(w4[0], w4[1], w4[2], w4[3]);
      *(float4*)&out[(size_t)T * 4 + (size_t)tok * 4] =
          make_float4(i4[0], i4[1], i4[2], i4[3]);
    }
  }
}

extern "C" void kernel_launch(void* const* d_in, const int* in_sizes, int n_in,
                              void* d_out, int out_size, void* d_ws,
                              size_t ws_size, hipStream_t stream) {
  const float* x = (const float*)d_in[0];
  const float* W = (const float*)d_in[1];
  float* out = (float*)d_out;
  int T = in_sizes[0] / 256;  // D = 256
  int nW = in_sizes[1];       // 16384
  int* meta = (int*)d_ws;
  unsigned short* wsp = (unsigned short*)((char*)d_ws + SPLIT_OFF);
  int* list = (int*)((char*)d_ws + LIST_OFF);
  int cap = (ws_size > LIST_OFF + 4) ? (int)((ws_size - LIST_OFF) / 4) : 0;
  hipLaunchKernelGGL(split_w, dim3((nW + 255) / 256), dim3(256), 0, stream, W,
                     wsp, nW, meta);
  hipLaunchKernelGGL(gate_kernel, dim3(T / 256), dim3(512), 0, stream, x, wsp,
                     out, meta, list, cap, T);
  hipLaunchKernelGGL(fix_kernel, dim3(2048), dim3(64), 0, stream, x, W, out,
                     meta, list, cap, T);
}

// Round 15
// 141.837 us; speedup vs baseline: 1.2043x; 1.2043x over previous
//
#include <hip/hip_runtime.h>
#include <hip/hip_bf16.h>
#include <stdint.h>

// MoE gate: T=524288, D=256, E=64, groups=2x32, topk=4.   [v12 revert]
// Pass 1: logits^T = W @ x^T via mfma_f32_16x16x32_bf16. W and x each split
//   into 2 bf16 truncation levels; 4 cross terms; dropped-term sigma ~1e-6
//   << DELTA=1e-4. W-split staged once per block into LDS (overlapped with
//   x prefetch, counted vmcnt + raw s_barrier -- no drain). x global->reg,
//   depth-2 prefetch, counted vmcnt. K-PERMUTED fragments: lane lg holds
//   k in {lg*4..+3} u {16+lg*4..+3} so each x load instruction covers 64B
//   contiguous per token row; W packed with the same permutation (MFMA
//   bijection invariance). 512-thread blocks, 32 tokens/wave, VGPR<=128.
// Pass 2: tokens with selection margin < DELTA recomputed exactly (np-order
//   fmaf chain) by fix_kernel (~1% of tokens).

typedef __attribute__((ext_vector_type(8))) short bf16x8;
typedef __attribute__((ext_vector_type(4))) float f32x4;
typedef __attribute__((ext_vector_type(4))) int i32x4;

#define SPLIT_OFF 1024
#define LIST_OFF 102400
#define DELTA 1e-4f

__device__ __forceinline__ f32x4 mf(const i32x4& a, const i32x4& b,
                                    const f32x4& c) {
  return __builtin_amdgcn_mfma_f32_16x16x32_bf16(
      __builtin_bit_cast(bf16x8, a), __builtin_bit_cast(bf16x8, b), c, 0, 0, 0);
}

// low short = hi16(e0), high short = hi16(e1)
__device__ __forceinline__ int packhi(unsigned e0, unsigned e1) {
  return (int)__builtin_amdgcn_perm(e1, e0, 0x07060302u);
}

__device__ __forceinline__ void gload16(const void* g, void* l) {
  __builtin_amdgcn_global_load_lds(
      (const __attribute__((address_space(1))) void*)g,
      (__attribute__((address_space(3))) void*)l, 16, 0, 0);
}

// W -> 2 bf16 truncation levels (h, m), packed in MFMA A-fragment
// chunk-major layout with the K-PERMUTED mapping: fragment slot kk of lane
// (lg*16+le) in frag(c, q=v*4+nt) holds W_v[e=nt*16+le]
// [k = c*32 + (kk>>2)*16 + lg*4 + (kk&3)]. Also zeroes the fix counter.
__global__ void split_w(const float* __restrict__ W,
                        unsigned short* __restrict__ ws, int n,
                        int* __restrict__ meta) {
  int i = blockIdx.x * 256 + threadIdx.x;
  if (i == 0) meta[0] = 0;
  if (i >= n) return;
  float w = W[i];
  unsigned u = __float_as_uint(w);
  unsigned uh = u & 0xFFFF0000u;
  float rf = w - __uint_as_float(uh);  // exact
  unsigned short lv[2];
  lv[0] = (unsigned short)(uh >> 16);
  lv[1] = (unsigned short)(__float_as_uint(rf) >> 16);
  int e = i >> 8, k = i & 255;
  int nt = e >> 4, le = e & 15;
  int c = k >> 5, kc = k & 31;
  int half = kc >> 4, lg = (kc >> 2) & 3, pos = kc & 3;
  int kk = half * 4 + pos;
  int lane = lg * 16 + le;
#pragma unroll
  for (int v = 0; v < 2; ++v)
    ws[(((c * 8 + v * 4 + nt) * 64) + lane) * 8 + kk] = lv[v];
}

struct XF2 { i32x4 h, m; };

__device__ __forceinline__ XF2 split2(f32x4 a, f32x4 b) {
  float xs[8] = {a[0], a[1], a[2], a[3], b[0], b[1], b[2], b[3]};
  XF2 f;
#pragma unroll
  for (int wd = 0; wd < 4; ++wd) {
    unsigned u0 = __float_as_uint(xs[2 * wd]);
    unsigned u1 = __float_as_uint(xs[2 * wd + 1]);
    f.h[wd] = packhi(u0, u1);
    float r0 = xs[2 * wd] - __uint_as_float(u0 & 0xFFFF0000u);      // exact
    float r1 = xs[2 * wd + 1] - __uint_as_float(u1 & 0xFFFF0000u);  // exact
    f.m[wd] = packhi(__float_as_uint(r0), __float_as_uint(r1));
  }
  return f;
}

// inline-asm global load with immediate offset; valid after matching WAITV.
#define GL(dst, ptr, OFF)                                     \
  asm volatile("global_load_dwordx4 %0, %1, off offset:%2"    \
               : "=v"(dst)                                    \
               : "v"(ptr), "n"(OFF))

#define WAITV(NSTR)                                         \
  do {                                                      \
    asm volatile("s_waitcnt vmcnt(" NSTR ")" ::: "memory"); \
    __builtin_amdgcn_sched_barrier(0);                      \
  } while (0)

__global__ __launch_bounds__(512, 4) void gate_kernel(
    const float* __restrict__ x, const unsigned short* __restrict__ wsp,
    float* __restrict__ out, int* __restrict__ meta, int* __restrict__ list,
    int cap, int T) {
  __shared__ i32x4 WL[4096];  // 64 KB: W-split fragments, chunk-major

  const int t = threadIdx.x;
  const int lane = t & 63;
  const int wid = t >> 6;    // 0..7
  const int le = lane & 15;  // token col / expert row within 16-tile
  const int lg = lane >> 4;  // k-quad group
  const int tokb = blockIdx.x * 256 + wid * 32;

  // K-permuted lane base: lane lg reads bytes [lg*16,+16) and [64+lg*16,+16)
  // of each 128B chunk.
  const float* xa0 = x + (size_t)(tokb + le) * 256 + lg * 4;
  const float* xa1 = xa0 + 16 * 256;

  f32x4 xbuf[2][4];  // depth-2, 2 buffers (freed buffer re-issued mid-ITER)
  f32x4 acc[4][2];   // [nt][tile]
#pragma unroll
  for (int nt = 0; nt < 4; ++nt)
#pragma unroll
    for (int t2 = 0; t2 < 2; ++t2) acc[nt][t2] = (f32x4)0.0f;

#define STAGE_X(c)                              \
  do {                                          \
    GL(xbuf[(c) & 1][0], xa0, (c) * 128);       \
    GL(xbuf[(c) & 1][1], xa0, (c) * 128 + 64);  \
    GL(xbuf[(c) & 1][2], xa1, (c) * 128);       \
    GL(xbuf[(c) & 1][3], xa1, (c) * 128 + 64);  \
  } while (0)

  // ITER c: wait x(c); split to bf16 frags (frees xbuf[c&1]); re-issue
  // x(c+2) into the freed buffer (WAR safe: reads precede the GL in issue
  // order); then W ds_reads + 32 MFMAs. No per-ITER barriers.
#define ITER(c, NSTR)                                               \
  {                                                                 \
    WAITV(NSTR);                                                    \
    XF2 b0 = split2(xbuf[(c) & 1][0], xbuf[(c) & 1][1]);            \
    XF2 b1 = split2(xbuf[(c) & 1][2], xbuf[(c) & 1][3]);            \
    if ((c) + 2 < 8) STAGE_X((c) + 2);                              \
    _Pragma("unroll") for (int nt = 0; nt < 4; ++nt) {              \
      i32x4 ah = WL[(((c) * 8 + nt) << 6) + lane];                  \
      i32x4 am = WL[(((c) * 8 + 4 + nt) << 6) + lane];              \
      acc[nt][0] = mf(ah, b0.h, acc[nt][0]);                        \
      acc[nt][0] = mf(ah, b0.m, acc[nt][0]);                        \
      acc[nt][0] = mf(am, b0.h, acc[nt][0]);                        \
      acc[nt][0] = mf(am, b0.m, acc[nt][0]);                        \
      acc[nt][1] = mf(ah, b1.h, acc[nt][1]);                        \
      acc[nt][1] = mf(ah, b1.m, acc[nt][1]);                        \
      acc[nt][1] = mf(am, b1.h, acc[nt][1]);                        \
      acc[nt][1] = mf(am, b1.m, acc[nt][1]);                        \
    }                                                               \
  }

  // ---- prologue: W gload_lds (8/thread, 64KB/block), then x chunks 0,1;
  // counted wait completes exactly W (x stays in flight); raw barrier. ----
  {
    const char* wsrc = (const char*)wsp + t * 16;
    char* wdst = (char*)WL + t * 16;
#pragma unroll
    for (int i = 0; i < 8; ++i) gload16(wsrc + i * 8192, wdst + i * 8192);
  }
  STAGE_X(0);
  STAGE_X(1);
  WAITV("8");
  __builtin_amdgcn_s_barrier();

  ITER(0, "4");
  ITER(1, "4");
  ITER(2, "4");
  ITER(3, "4");
  ITER(4, "4");
  ITER(5, "4");
  ITER(6, "4");
  ITER(7, "0");

  // epilogue: D col=token(le), row=expert=nt*16+4*lg+j. LOGIT-domain select.
#pragma unroll
  for (int tt = 0; tt < 2; ++tt) {
    float l[16];
#pragma unroll
    for (int nt = 0; nt < 4; ++nt)
#pragma unroll
      for (int j = 0; j < 4; ++j) l[nt * 4 + j] = acc[nt][tt][j];

    float g0 = l[0], g1 = l[8];
#pragma unroll
    for (int j = 1; j < 8; ++j) {
      g0 = fmaxf(g0, l[j]);
      g1 = fmaxf(g1, l[8 + j]);
    }
    g0 = fmaxf(g0, __shfl_xor(g0, 16));
    g0 = fmaxf(g0, __shfl_xor(g0, 32));
    g1 = fmaxf(g1, __shfl_xor(g1, 16));
    g1 = fmaxf(g1, __shfl_xor(g1, 32));
    const int g = (g1 > g0) ? 1 : 0;  // tie -> group 0
    const float m = fmaxf(g0, g1);

    float sum = 0.f;
#pragma unroll
    for (int k = 0; k < 16; ++k) sum += __expf(l[k] - m);
    sum += __shfl_xor(sum, 16);
    sum += __shfl_xor(sum, 32);
    const float inv = 1.0f / sum;

    float c[8];
    int ce[8];
#pragma unroll
    for (int j2 = 0; j2 < 8; ++j2) {
      c[j2] = l[g * 8 + j2];
      ce[j2] = (2 * g + (j2 >> 2)) * 16 + 4 * lg + (j2 & 3);
    }

    float v5[5];
    int e5[5];
#pragma unroll
    for (int it = 0; it < 5; ++it) {
      float bv = c[0];
      int be = ce[0];
#pragma unroll
      for (int j2 = 1; j2 < 8; ++j2) {  // strict > keeps lowest index
        bool gt = c[j2] > bv;
        bv = gt ? c[j2] : bv;
        be = gt ? ce[j2] : be;
      }
#pragma unroll
      for (int st = 0; st < 2; ++st) {
        int msk = 16 << st;
        float ov = __shfl_xor(bv, msk);
        int oe = __shfl_xor(be, msk);
        bool tk = (ov > bv) || (ov == bv && oe < be);
        bv = tk ? ov : bv;
        be = tk ? oe : be;
      }
      v5[it] = bv;
      e5[it] = be;
#pragma unroll
      for (int j2 = 0; j2 < 8; ++j2)
        c[j2] = (ce[j2] == be) ? -3.0e38f : c[j2];
    }

    float ming = fabsf(g0 - g1);
#pragma unroll
    for (int it = 0; it < 4; ++it) ming = fminf(ming, v5[it] - v5[it + 1]);

    if (lg == 0) {
      size_t trow = (size_t)tokb + tt * 16 + le;
      *(float4*)&out[trow * 4] =
          make_float4(__expf(v5[0] - m) * inv, __expf(v5[1] - m) * inv,
                      __expf(v5[2] - m) * inv, __expf(v5[3] - m) * inv);
      *(float4*)&out[(size_t)T * 4 + trow * 4] = make_float4(
          (float)e5[0], (float)e5[1], (float)e5[2], (float)e5[3]);
      if (ming < DELTA) {
        int p = atomicAdd(meta, 1);
        if (p < cap) list[p] = (int)trow;
      }
    }
  }
}

// exact recompute of flagged tokens: one wave per token, lane = expert.
__global__ __launch_bounds__(64) void fix_kernel(
    const float* __restrict__ x, const float* __restrict__ W,
    float* __restrict__ out, const int* __restrict__ meta,
    const int* __restrict__ list, int cap, int T) {
  const int e = threadIdx.x;
  int cnt = meta[0];
  cnt = cnt < cap ? cnt : cap;
  for (int i = blockIdx.x; i < cnt; i += gridDim.x) {
    const int tok = list[i];
    const float* xr = x + (size_t)tok * 256;
    const float* wr = W + (size_t)e * 256;
    float acc = 0.f;
#pragma unroll 8
    for (int d = 0; d < 256; d += 4) {  // single-acc ascending-d fmaf chain
      float4 xv = *(const float4*)(xr + d);
      float4 wv = *(const float4*)(wr + d);
      acc = fmaf(xv.x, wv.x, acc);
      acc = fmaf(xv.y, wv.y, acc);
      acc = fmaf(xv.z, wv.z, acc);
      acc = fmaf(xv.w, wv.w, acc);
    }
    float gm = acc;
#pragma unroll
    for (int st = 0; st < 5; ++st) gm = fmaxf(gm, __shfl_xor(gm, 1 << st));
    float om = __shfl_xor(gm, 32);
    float g0 = (e < 32) ? gm : om;
    float g1 = (e < 32) ? om : gm;
    const int g = (g1 > g0) ? 1 : 0;
    const float m = fmaxf(g0, g1);
    float sum = __expf(acc - m);
#pragma unroll
    for (int st = 0; st < 6; ++st) sum += __shfl_xor(sum, 1 << st);
    const float inv = 1.0f / sum;

    float cand = ((e >> 5) == g) ? acc : -3.0e38f;
    float w4[4], i4[4];
#pragma unroll
    for (int it = 0; it < 4; ++it) {
      float bv = cand;
      int be = e;
#pragma unroll
      for (int st = 0; st < 6; ++st) {
        int msk = 1 << st;
        float ov = __shfl_xor(bv, msk);
        int oe = __shfl_xor(be, msk);
        bool tk = (ov > bv) || (ov == bv && oe < be);
        bv = tk ? ov : bv;
        be = tk ? oe : be;
      }
      w4[it] = __expf(bv - m) * inv;
      i4[it] = (float)be;
      if (e == be) cand = -3.0e38f;
    }
    if (e == 0) {
      *(float4*)&out[(size_t)tok * 4] = make_float4(w4[0], w4[1], w4[2], w4[3]);
      *(float4*)&out[(size_t)T * 4 + (size_t)tok * 4] =
          make_float4(i4[0], i4[1], i4[2], i4[3]);
    }
  }
}

extern "C" void kernel_launch(void* const* d_in, const int* in_sizes, int n_in,
                              void* d_out, int out_size, void* d_ws,
                              size_t ws_size, hipStream_t stream) {
  const float* x = (const float*)d_in[0];
  const float* W = (const float*)d_in[1];
  float* out = (float*)d_out;
  int T = in_sizes[0] / 256;  // D = 256
  int nW = in_sizes[1];       // 16384
  int* meta = (int*)d_ws;
  unsigned short* wsp = (unsigned short*)((char*)d_ws + SPLIT_OFF);
  int* list = (int*)((char*)d_ws + LIST_OFF);
  int cap = (ws_size > LIST_OFF + 4) ? (int)((ws_size - LIST_OFF) / 4) : 0;
  hipLaunchKernelGGL(split_w, dim3((nW + 255) / 256), dim3(256), 0, stream, W,
                     wsp, nW, meta);
  hipLaunchKernelGGL(gate_kernel, dim3(T / 256), dim3(512), 0, stream, x, wsp,
                     out, meta, list, cap, T);
  hipLaunchKernelGGL(fix_kernel, dim3(2048), dim3(64), 0, stream, x, W, out,
                     meta, list, cap, T);
}